// Round 2
// baseline (278.550 us; speedup 1.0000x reference)
//
#include <hip/hip_runtime.h>
#include <math.h>

#define B_    4096
#define N_    10
#define DIN_  32
#define D_    128
#define PHI_  256
#define RHO_  128
#define L_    3
#define EPS_  1e-5f

// ---- fp16 helpers (bits in short) ----
__device__ __forceinline__ short f2hs(float f) {            // f32 -> fp16 RNE
    union { _Float16 h; short s; } u;
    u.h = (_Float16)f;
    return u.s;
}
__device__ __forceinline__ float hs2f(short s) {
    union { _Float16 h; short s; } u;
    u.s = s;
    return (float)u.h;
}

typedef short    s16x8 __attribute__((ext_vector_type(8)));
typedef _Float16 h16x8 __attribute__((ext_vector_type(8)));
typedef float    f32x4 __attribute__((ext_vector_type(4)));
typedef float    v2f   __attribute__((ext_vector_type(2)));

__device__ __forceinline__ h16x8 ld8h(const short* p) {
    union { s16x8 s; h16x8 h; } u;
    u.s = *(const s16x8*)p;
    return u.h;
}

__device__ __forceinline__ v2f splat2(float s) { v2f r; r.x = s; r.y = s; return r; }
__device__ __forceinline__ v2f fma2(v2f a, v2f b, v2f c) { return __builtin_elementwise_fma(a, b, c); }

// ---- d_ws layout (fp16 elements). Fragment unit = 64 lanes x 8 el = 512 el.
// For matrix W[K][N]: frag (nt,ks) at ((nt*KS+ks)*64+lane)*8, lane holds
// W[ks*32+(lane>>4)*8+j][nt*16+(lane&15)], j=0..7  (B-operand layout, 16x16x32)
#define WS_WE1 0
#define WS_WE2 4096
#define WS_RGW 20480
#define WS_RGR 118784
#define WS_L1  167936
#define WS_L2  217088
#define WS_P1  266240
#define WS_P2  299008
#define WS_R1  364544

// ================= prep kernel: fp32 weights -> fp16 B-fragments ==========
__global__ __launch_bounds__(64)
void prep_weights(const float* __restrict__ We1, const float* __restrict__ We2,
                  const float* __restrict__ rgw, const float* __restrict__ rgr,
                  const float* __restrict__ l1w, const float* __restrict__ l2w,
                  const float* __restrict__ p1w, const float* __restrict__ p2w,
                  const float* __restrict__ r1w, short* __restrict__ ws)
{
    int bi = blockIdx.x, l = threadIdx.x;
    const float* src; int KS, Nw, dstOff, tt;
    if      (bi <   8) { src = We1; KS = 1; Nw = 128; dstOff = WS_WE1; tt = bi; }
    else if (bi <  40) { src = We2; KS = 4; Nw = 128; dstOff = WS_WE2; tt = bi - 8; }
    else if (bi < 232) { int m = (bi - 40) >> 5;  src = rgw + m * 16384; KS = 4; Nw = 128; dstOff = WS_RGW + m * 16384; tt = (bi - 40)  & 31; }
    else if (bi < 328) { int m = (bi - 232) >> 5; src = rgr + m * 16384; KS = 4; Nw = 128; dstOff = WS_RGR + m * 16384; tt = (bi - 232) & 31; }
    else if (bi < 424) { int m = (bi - 328) >> 5; src = l1w + m * 16384; KS = 4; Nw = 128; dstOff = WS_L1  + m * 16384; tt = (bi - 328) & 31; }
    else if (bi < 520) { int m = (bi - 424) >> 5; src = l2w + m * 16384; KS = 4; Nw = 128; dstOff = WS_L2  + m * 16384; tt = (bi - 424) & 31; }
    else if (bi < 584) { src = p1w; KS = 4; Nw = 256; dstOff = WS_P1; tt = bi - 520; }
    else if (bi < 712) { src = p2w; KS = 8; Nw = 256; dstOff = WS_P2; tt = bi - 584; }
    else               { src = r1w; KS = 8; Nw = 128; dstOff = WS_R1; tt = bi - 712; }
    int nt = tt / KS, ks = tt - nt * KS;
    int kbase = ks * 32 + (l >> 4) * 8;
    int col   = nt * 16 + (l & 15);
    union { short s[8]; int4 v; } u;
#pragma unroll
    for (int j = 0; j < 8; ++j)
        u.s[j] = f2hs(src[(size_t)(kbase + j) * Nw + col]);
    *(int4*)(ws + dstOff + ((size_t)tt * 64 + l) * 8) = u.v;
}

// ================= main kernel: 1 block (4 waves) = 1 graph ================
// A-operand layout: lane holds A[m=lane&15][k=(lane>>4)*8+j]; rows >=10 clamped
// C/D layout: col = lane&15, row = (lane>>4)*4 + reg
// Wave wv owns output tiles nt = wv*NTP .. wv*NTP+NTP-1 (callers pre-offset
// the weight base by ntBase*KS*512, bias/dst by ntBase*16).

template<int NTP>
__device__ __forceinline__ void initC(f32x4* acc, const float* __restrict__ bias, int c16) {
#pragma unroll
    for (int j = 0; j < NTP; ++j) {
        float bv = bias[j * 16 + c16];
        acc[j] = (f32x4){bv, bv, bv, bv};
    }
}

template<int KS, int NTP>
__device__ __forceinline__ void mm_a16(const short* __restrict__ Wf, const short* __restrict__ Ab,
                                       int ldA, int mrow, int q, int l, f32x4* acc) {
#pragma unroll
    for (int ks = 0; ks < KS; ++ks) {
        h16x8 a = ld8h(Ab + mrow * ldA + ks * 32 + q * 8);
#pragma unroll
        for (int j = 0; j < NTP; ++j) {
            h16x8 bv = ld8h(Wf + ((size_t)(j * KS + ks) * 64 + l) * 8);
            acc[j] = __builtin_amdgcn_mfma_f32_16x16x32_f16(a, bv, acc[j], 0, 0, 0);
        }
    }
}

template<int KS, int NTP>
__device__ __forceinline__ void mm_a32(const short* __restrict__ Wf, const float* __restrict__ Af,
                                       int ldA, int mrow, int q, int l, f32x4* acc) {
#pragma unroll
    for (int ks = 0; ks < KS; ++ks) {
        const float* p = Af + mrow * ldA + ks * 32 + q * 8;
        f32x4 x0 = *(const f32x4*)p;
        f32x4 x1 = *(const f32x4*)(p + 4);
        h16x8 a;
        a[0] = (_Float16)x0[0]; a[1] = (_Float16)x0[1]; a[2] = (_Float16)x0[2]; a[3] = (_Float16)x0[3];
        a[4] = (_Float16)x1[0]; a[5] = (_Float16)x1[1]; a[6] = (_Float16)x1[2]; a[7] = (_Float16)x1[3];
#pragma unroll
        for (int j = 0; j < NTP; ++j) {
            h16x8 bv = ld8h(Wf + ((size_t)(j * KS + ks) * 64 + l) * 8);
            acc[j] = __builtin_amdgcn_mfma_f32_16x16x32_f16(a, bv, acc[j], 0, 0, 0);
        }
    }
}

// store C tiles as fp16 into LDS (row-major, ldD elements), rows >= 10 dropped.
// dst must be pre-offset by ntBase*16.
template<int NTP, bool RELU>
__device__ __forceinline__ void storeC16(const f32x4* acc, short* __restrict__ dst,
                                         int ldD, int q, int c16) {
#pragma unroll
    for (int j = 0; j < NTP; ++j) {
#pragma unroll
        for (int i = 0; i < 4; ++i) {
            int r = q * 4 + i;
            if (r < 10) {
                float v = acc[j][i];
                if (RELU) v = fmaxf(v, 0.f);
                dst[r * ldD + j * 16 + c16] = f2hs(v);
            }
        }
    }
}

#define HLD 132   // Hf row stride (f32)
#define MLD 136   // Me row stride (fp16)
#define GLD 264   // Gb row stride (fp16)

__global__ __launch_bounds__(256, 8)
void gcn_main(const float* __restrict__ A, const float* __restrict__ X,
              const int* __restrict__ home_mask,
              const float* __restrict__ be1, const float* __restrict__ be2,
              const float* __restrict__ rgcn_b,
              const float* __restrict__ l1b, const float* __restrict__ l2b,
              const float* __restrict__ ln_g, const float* __restrict__ ln_b,
              const float* __restrict__ p1b, const float* __restrict__ p2b,
              const float* __restrict__ r1b, const float* __restrict__ r2w,
              const short* __restrict__ ws, float* __restrict__ out)
{
    const int b   = blockIdx.x;
    const int tid = threadIdx.x;       // 0..255
    const int wv  = tid >> 6;          // wave 0..3
    const int l   = tid & 63;          // lane
    const int q   = l >> 4;
    const int c16 = l & 15;
    const int mrow = (c16 < 10) ? c16 : 9;

    __shared__ __align__(16) float HfS[N_ * HLD];     // residual H, fp32
    __shared__ __align__(16) short Me0S[N_ * MLD];    // mean0 (fp16)
    __shared__ __align__(16) short Me1S[N_ * MLD];    // mean1 (fp16)
    __shared__ __align__(16) short GbS[N_ * GLD];     // staging (256 cols)
    __shared__ __align__(16) short RhoS[2 * 256];     // [hs ; aws] fp16
    __shared__ float AabsS[100], M1S[100];
    __shared__ float invc0S[N_], invc1S[N_];
    __shared__ float hmfS[16], awfS[16];
    __shared__ float dS[4];

    // ---- phase 0: stage A/masks + embed1 (no LDS deps) ----
    if (tid < 100) {
        float a = A[(size_t)b * 100 + tid];
        AabsS[tid] = fabsf(a);
        M1S[tid]  = (a > 0.f) ? 1.f : 0.f;
    }
    if (tid < 16) {
        float hm = 0.f, aw = 0.f;
        if (tid < 10) { hm = (float)home_mask[b * N_ + tid]; aw = 1.f - hm; }
        hmfS[tid] = hm; awfS[tid] = aw;
    }
    {   // embed1: H1 = relu(X@We1 + be1) -> Gb[:,0:128]; wave wv: nt = 2wv..2wv+1
        f32x4 acc[2];
        initC<2>(acc, be1 + wv * 32, c16);
        const float* xg = X + (size_t)b * (N_ * DIN_) + mrow * DIN_ + q * 8;
        f32x4 x0 = *(const f32x4*)xg;
        f32x4 x1 = *(const f32x4*)(xg + 4);
        h16x8 a;
        a[0] = (_Float16)x0[0]; a[1] = (_Float16)x0[1]; a[2] = (_Float16)x0[2]; a[3] = (_Float16)x0[3];
        a[4] = (_Float16)x1[0]; a[5] = (_Float16)x1[1]; a[6] = (_Float16)x1[2]; a[7] = (_Float16)x1[3];
#pragma unroll
        for (int j = 0; j < 2; ++j) {
            h16x8 bv = ld8h(ws + WS_WE1 + ((size_t)(wv * 2 + j) * 64 + l) * 8);
            acc[j] = __builtin_amdgcn_mfma_f32_16x16x32_f16(a, bv, acc[j], 0, 0, 0);
        }
        storeC16<2, true>(acc, GbS + wv * 32, GLD, q, c16);
    }
    __syncthreads();

    // ---- phase 1: invc (from M1S) + embed2 ----
    if (tid < 10) {
        float c1 = 0.f;
#pragma unroll
        for (int i = 0; i < 10; ++i) c1 += M1S[i * 10 + tid];
        invc1S[tid] = 1.f / fmaxf(c1, 1.f);
        invc0S[tid] = 1.f / fmaxf(10.f - c1, 1.f);
    }
    {   // embed2: H = H1@We2 + be2 -> Hf (fp32)
        f32x4 acc[2];
        initC<2>(acc, be2 + wv * 32, c16);
        mm_a16<4, 2>(ws + WS_WE2 + (size_t)wv * 4096, GbS, GLD, mrow, q, l, acc);
        float* hb = HfS + wv * 32;
#pragma unroll
        for (int j = 0; j < 2; ++j)
#pragma unroll
            for (int i = 0; i < 4; ++i) {
                int r = q * 4 + i;
                if (r < 10) hb[r * HLD + j * 16 + c16] = acc[j][i];
            }
    }
    __syncthreads();

    // ---- layers ----
    for (int ll = 0; ll < L_; ++ll) {
        // means: wave wv owns target rows j = wv, wv+4, wv+8 (lane owns cols 2l,2l+1)
        {
            v2f hv[N_];
#pragma unroll
            for (int i = 0; i < N_; ++i) hv[i] = *(const v2f*)(HfS + i * HLD + 2 * l);
            v2f st = hv[0];
#pragma unroll
            for (int i = 1; i < N_; ++i) st += hv[i];
            for (int j = wv; j < 10; j += 4) {
                v2f s1 = splat2(0.f);
#pragma unroll
                for (int i = 0; i < N_; ++i) s1 = fma2(splat2(M1S[i * 10 + j]), hv[i], s1);
                v2f m0 = (st - s1) * splat2(invc0S[j]);
                v2f m1 = s1 * splat2(invc1S[j]);
                short2 w0; w0.x = f2hs(m0.x); w0.y = f2hs(m0.y);
                short2 w1; w1.x = f2hs(m1.x); w1.y = f2hs(m1.y);
                *(short2*)(Me0S + j * MLD + 2 * l) = w0;
                *(short2*)(Me1S + j * MLD + 2 * l) = w1;
            }
        }
        __syncthreads();
        // H2 = mean0@W0 + mean1@W1 + H@root + b -> Gb[:,0:128]
        {
            f32x4 acc[2];
            initC<2>(acc, rgcn_b + ll * D_ + wv * 32, c16);
            mm_a16<4, 2>(ws + WS_RGW + (size_t)(ll * 2 + 0) * 16384 + (size_t)wv * 4096, Me0S, MLD, mrow, q, l, acc);
            mm_a16<4, 2>(ws + WS_RGW + (size_t)(ll * 2 + 1) * 16384 + (size_t)wv * 4096, Me1S, MLD, mrow, q, l, acc);
            mm_a32<4, 2>(ws + WS_RGR + (size_t)ll * 16384 + (size_t)wv * 4096, HfS, HLD, mrow, q, l, acc);
            storeC16<2, false>(acc, GbS + wv * 32, GLD, q, c16);
        }
        __syncthreads();
        // agg + LN + relu: wave wv owns rows i = wv, wv+4, wv+8.
        // reads Gb[:,0:128] (H2), writes Gb[:,128:256] (no in-place hazard).
        {
            v2f lg2 = *(const v2f*)(ln_g + 2 * l);
            v2f lb2 = *(const v2f*)(ln_b + 2 * l);
            v2f hv2[N_];
#pragma unroll
            for (int jj = 0; jj < N_; ++jj) {
                short2 hh = *(const short2*)(GbS + jj * GLD + 2 * l);
                hv2[jj].x = hs2f(hh.x); hv2[jj].y = hs2f(hh.y);
            }
            for (int i = wv; i < 10; i += 4) {
                v2f ag = splat2(0.f);
#pragma unroll
                for (int jj = 0; jj < N_; ++jj)
                    ag = fma2(splat2(AabsS[i * 10 + jj]), hv2[jj], ag);
                float s  = ag.x + ag.y;
                float ss = fmaf(ag.x, ag.x, ag.y * ag.y);
#pragma unroll
                for (int off = 32; off > 0; off >>= 1) {
                    s  += __shfl_xor(s,  off);
                    ss += __shfl_xor(ss, off);
                }
                float mu   = s * (1.f / 128.f);
                float var  = ss * (1.f / 128.f) - mu * mu;
                float rstd = rsqrtf(var + EPS_);
                v2f v = fma2((ag - splat2(mu)) * splat2(rstd), lg2, lb2);
                short2 wvv; wvv.x = f2hs(fmaxf(v.x, 0.f)); wvv.y = f2hs(fmaxf(v.y, 0.f));
                *(short2*)(GbS + i * GLD + 128 + 2 * l) = wvv;
            }
        }
        __syncthreads();
        // MLP1: relu(LNout @ l1w + l1b): reads Gb[:,128:256], writes Gb[:,0:128]
        {
            f32x4 acc[2];
            initC<2>(acc, l1b + ll * D_ + wv * 32, c16);
            mm_a16<4, 2>(ws + WS_L1 + (size_t)ll * 16384 + (size_t)wv * 4096, GbS + 128, GLD, mrow, q, l, acc);
            storeC16<2, true>(acc, GbS + wv * 32, GLD, q, c16);
        }
        __syncthreads();
        // MLP2: hidden @ l2w + l2b: reads Gb[:,0:128], Hf += result
        {
            f32x4 acc[2];
            initC<2>(acc, l2b + ll * D_ + wv * 32, c16);
            mm_a16<4, 2>(ws + WS_L2 + (size_t)ll * 16384 + (size_t)wv * 4096, GbS, GLD, mrow, q, l, acc);
            float* hb = HfS + wv * 32;
#pragma unroll
            for (int j = 0; j < 2; ++j)
#pragma unroll
                for (int i = 0; i < 4; ++i) {
                    int r = q * 4 + i;
                    if (r < 10) hb[r * HLD + j * 16 + c16] += acc[j][i];
                }
        }
        __syncthreads();
    }

    // ---- phi1: relu(H @ p1w + p1b) -> Gb[:,0:256]; wave wv: nt = 4wv..4wv+3 ----
    {
        f32x4 acc[4];
        initC<4>(acc, p1b + wv * 64, c16);
        mm_a32<4, 4>(ws + WS_P1 + (size_t)wv * 8192, HfS, HLD, mrow, q, l, acc);
        storeC16<4, true>(acc, GbS + wv * 64, GLD, q, c16);
    }
    __syncthreads();
    // ---- phi2 + masked column sums -> RhoS [hs;aws]; wave wv: t = 4wv..4wv+3 ----
    {
        f32x4 acc[4];
        initC<4>(acc, p2b + wv * 64, c16);
        mm_a16<8, 4>(ws + WS_P2 + (size_t)wv * 16384, GbS, GLD, mrow, q, l, acc);
        float hm0 = hmfS[q * 4 + 0], hm1 = hmfS[q * 4 + 1], hm2 = hmfS[q * 4 + 2], hm3 = hmfS[q * 4 + 3];
        float aw0 = awfS[q * 4 + 0], aw1 = awfS[q * 4 + 1], aw2 = awfS[q * 4 + 2], aw3 = awfS[q * 4 + 3];
#pragma unroll
        for (int t = 0; t < 4; ++t) {
            float v0 = fmaxf(acc[t][0], 0.f), v1 = fmaxf(acc[t][1], 0.f);
            float v2 = fmaxf(acc[t][2], 0.f), v3 = fmaxf(acc[t][3], 0.f);
            float hp = hm0 * v0 + hm1 * v1 + hm2 * v2 + hm3 * v3;
            float ap = aw0 * v0 + aw1 * v1 + aw2 * v2 + aw3 * v3;
            hp += __shfl_xor(hp, 16); hp += __shfl_xor(hp, 32);
            ap += __shfl_xor(ap, 16); ap += __shfl_xor(ap, 32);
            if (l < 16) {
                RhoS[(wv * 4 + t) * 16 + l]       = f2hs(hp);
                RhoS[256 + (wv * 4 + t) * 16 + l] = f2hs(ap);
            }
        }
    }
    __syncthreads();
    // ---- rho: relu([hs;aws] @ r1w + r1b) @ r2w; wave wv: t = 2wv..2wv+1 ----
    {
        f32x4 acc[2];
        initC<2>(acc, r1b + wv * 32, c16);
        const int rr = (c16 < 2) ? c16 : 0;
        mm_a16<8, 2>(ws + WS_R1 + (size_t)wv * 8192, RhoS, 256, rr, q, l, acc);
        float d = 0.f;
        if (q == 0) {
#pragma unroll
            for (int t = 0; t < 2; ++t) {
                float vh = fmaxf(acc[t][0], 0.f);
                float va = fmaxf(acc[t][1], 0.f);
                d = fmaf(vh - va, r2w[(wv * 2 + t) * 16 + c16], d);
            }
        }
#pragma unroll
        for (int off = 32; off > 0; off >>= 1) d += __shfl_xor(d, off);
        if (l == 0) dS[wv] = d;
    }
    __syncthreads();
    if (tid == 0) out[b] = 0.5f + 0.5f * tanhf(dS[0] + dS[1] + dS[2] + dS[3]);
}

extern "C" void kernel_launch(void* const* d_in, const int* in_sizes, int n_in,
                              void* d_out, int out_size, void* d_ws, size_t ws_size,
                              hipStream_t stream) {
    const float* A         = (const float*)d_in[0];
    const float* X         = (const float*)d_in[1];
    const int*   home_mask = (const int*)  d_in[2];
    const float* We1       = (const float*)d_in[3];
    const float* be1       = (const float*)d_in[4];
    const float* We2       = (const float*)d_in[5];
    const float* be2       = (const float*)d_in[6];
    const float* rgcn_w    = (const float*)d_in[7];
    const float* rgcn_root = (const float*)d_in[8];
    const float* rgcn_b    = (const float*)d_in[9];
    const float* l1w       = (const float*)d_in[10];
    const float* l1b       = (const float*)d_in[11];
    const float* l2w       = (const float*)d_in[12];
    const float* l2b       = (const float*)d_in[13];
    const float* ln_g      = (const float*)d_in[14];
    const float* ln_b      = (const float*)d_in[15];
    const float* p1w       = (const float*)d_in[16];
    const float* p1b       = (const float*)d_in[17];
    const float* p2w       = (const float*)d_in[18];
    const float* p2b       = (const float*)d_in[19];
    const float* r1w       = (const float*)d_in[20];
    const float* r1b       = (const float*)d_in[21];
    const float* r2w       = (const float*)d_in[22];

    short* ws = (short*)d_ws;

    prep_weights<<<776, 64, 0, stream>>>(We1, We2, rgcn_w, rgcn_root,
                                         l1w, l2w, p1w, p2w, r1w, ws);
    gcn_main<<<B_, 256, 0, stream>>>(A, X, home_mask, be1, be2, rgcn_b,
                                     l1b, l2b, ln_g, ln_b, p1b, p2b,
                                     r1b, r2w, ws, (float*)d_out);
}

// Round 3
// 256.819 us; speedup vs baseline: 1.0846x; 1.0846x over previous
//
#include <hip/hip_runtime.h>
#include <math.h>

#define B_    4096
#define N_    10
#define DIN_  32
#define D_    128
#define PHI_  256
#define RHO_  128
#define L_    3
#define EPS_  1e-5f

// ---- fp16 helpers (bits in short) ----
__device__ __forceinline__ short f2hs(float f) {            // f32 -> fp16 RNE
    union { _Float16 h; short s; } u;
    u.h = (_Float16)f;
    return u.s;
}
__device__ __forceinline__ float hs2f(short s) {
    union { _Float16 h; short s; } u;
    u.s = s;
    return (float)u.h;
}

typedef short    s16x8 __attribute__((ext_vector_type(8)));
typedef _Float16 h16x8 __attribute__((ext_vector_type(8)));
typedef float    f32x4 __attribute__((ext_vector_type(4)));
typedef float    v2f   __attribute__((ext_vector_type(2)));

__device__ __forceinline__ h16x8 ld8h(const short* p) {
    union { s16x8 s; h16x8 h; } u;
    u.s = *(const s16x8*)p;
    return u.h;
}

__device__ __forceinline__ v2f splat2(float s) { v2f r; r.x = s; r.y = s; return r; }
__device__ __forceinline__ v2f fma2(v2f a, v2f b, v2f c) { return __builtin_elementwise_fma(a, b, c); }

// ---- d_ws layout (fp16 elements). Fragment unit = 64 lanes x 8 el = 512 el.
// For matrix W[K][N]: frag (nt,ks) at ((nt*KS+ks)*64+lane)*8, lane holds
// W[ks*32+(lane>>4)*8+j][nt*16+(lane&15)], j=0..7  (B-operand layout, 16x16x32)
#define WS_WE1 0
#define WS_WE2 4096
#define WS_RGW 20480
#define WS_RGR 118784
#define WS_L1  167936
#define WS_L2  217088
#define WS_P1  266240
#define WS_P2  299008
#define WS_R1  364544

// ================= prep kernel: fp32 weights -> fp16 B-fragments ==========
__global__ __launch_bounds__(64)
void prep_weights(const float* __restrict__ We1, const float* __restrict__ We2,
                  const float* __restrict__ rgw, const float* __restrict__ rgr,
                  const float* __restrict__ l1w, const float* __restrict__ l2w,
                  const float* __restrict__ p1w, const float* __restrict__ p2w,
                  const float* __restrict__ r1w, short* __restrict__ ws)
{
    int bi = blockIdx.x, l = threadIdx.x;
    const float* src; int KS, Nw, dstOff, tt;
    if      (bi <   8) { src = We1; KS = 1; Nw = 128; dstOff = WS_WE1; tt = bi; }
    else if (bi <  40) { src = We2; KS = 4; Nw = 128; dstOff = WS_WE2; tt = bi - 8; }
    else if (bi < 232) { int m = (bi - 40) >> 5;  src = rgw + m * 16384; KS = 4; Nw = 128; dstOff = WS_RGW + m * 16384; tt = (bi - 40)  & 31; }
    else if (bi < 328) { int m = (bi - 232) >> 5; src = rgr + m * 16384; KS = 4; Nw = 128; dstOff = WS_RGR + m * 16384; tt = (bi - 232) & 31; }
    else if (bi < 424) { int m = (bi - 328) >> 5; src = l1w + m * 16384; KS = 4; Nw = 128; dstOff = WS_L1  + m * 16384; tt = (bi - 328) & 31; }
    else if (bi < 520) { int m = (bi - 424) >> 5; src = l2w + m * 16384; KS = 4; Nw = 128; dstOff = WS_L2  + m * 16384; tt = (bi - 424) & 31; }
    else if (bi < 584) { src = p1w; KS = 4; Nw = 256; dstOff = WS_P1; tt = bi - 520; }
    else if (bi < 712) { src = p2w; KS = 8; Nw = 256; dstOff = WS_P2; tt = bi - 584; }
    else               { src = r1w; KS = 8; Nw = 128; dstOff = WS_R1; tt = bi - 712; }
    int nt = tt / KS, ks = tt - nt * KS;
    int kbase = ks * 32 + (l >> 4) * 8;
    int col   = nt * 16 + (l & 15);
    union { short s[8]; int4 v; } u;
#pragma unroll
    for (int j = 0; j < 8; ++j)
        u.s[j] = f2hs(src[(size_t)(kbase + j) * Nw + col]);
    *(int4*)(ws + dstOff + ((size_t)tt * 64 + l) * 8) = u.v;
}

// ================= main kernel: 1 block (4 waves) = 1 graph ================
// A-operand layout: lane holds A[m=lane&15][k=(lane>>4)*8+j]; rows >=10 clamped
// C/D layout: col = lane&15, row = (lane>>4)*4 + reg
// Wave wv owns output tiles nt = wv*NTP .. wv*NTP+NTP-1 (callers pre-offset
// the weight base by ntBase*KS*512, bias/dst by ntBase*16).

template<int NTP>
__device__ __forceinline__ void initC(f32x4* acc, const float* __restrict__ bias, int c16) {
#pragma unroll
    for (int j = 0; j < NTP; ++j) {
        float bv = bias[j * 16 + c16];
        acc[j] = (f32x4){bv, bv, bv, bv};
    }
}

template<int KS, int NTP>
__device__ __forceinline__ void mm_a16(const short* __restrict__ Wf, const short* __restrict__ Ab,
                                       int ldA, int mrow, int q, int l, f32x4* acc) {
#pragma unroll
    for (int ks = 0; ks < KS; ++ks) {
        h16x8 a = ld8h(Ab + mrow * ldA + ks * 32 + q * 8);
#pragma unroll
        for (int j = 0; j < NTP; ++j) {
            h16x8 bv = ld8h(Wf + ((size_t)(j * KS + ks) * 64 + l) * 8);
            acc[j] = __builtin_amdgcn_mfma_f32_16x16x32_f16(a, bv, acc[j], 0, 0, 0);
        }
    }
}

template<int KS, int NTP>
__device__ __forceinline__ void mm_a32(const short* __restrict__ Wf, const float* __restrict__ Af,
                                       int ldA, int mrow, int q, int l, f32x4* acc) {
#pragma unroll
    for (int ks = 0; ks < KS; ++ks) {
        const float* p = Af + mrow * ldA + ks * 32 + q * 8;
        f32x4 x0 = *(const f32x4*)p;
        f32x4 x1 = *(const f32x4*)(p + 4);
        h16x8 a;
        a[0] = (_Float16)x0[0]; a[1] = (_Float16)x0[1]; a[2] = (_Float16)x0[2]; a[3] = (_Float16)x0[3];
        a[4] = (_Float16)x1[0]; a[5] = (_Float16)x1[1]; a[6] = (_Float16)x1[2]; a[7] = (_Float16)x1[3];
#pragma unroll
        for (int j = 0; j < NTP; ++j) {
            h16x8 bv = ld8h(Wf + ((size_t)(j * KS + ks) * 64 + l) * 8);
            acc[j] = __builtin_amdgcn_mfma_f32_16x16x32_f16(a, bv, acc[j], 0, 0, 0);
        }
    }
}

// store C tiles as fp16 into LDS (row-major, ldD elements), rows >= 10 dropped.
// dst must be pre-offset by ntBase*16.
template<int NTP, bool RELU>
__device__ __forceinline__ void storeC16(const f32x4* acc, short* __restrict__ dst,
                                         int ldD, int q, int c16) {
#pragma unroll
    for (int j = 0; j < NTP; ++j) {
#pragma unroll
        for (int i = 0; i < 4; ++i) {
            int r = q * 4 + i;
            if (r < 10) {
                float v = acc[j][i];
                if (RELU) v = fmaxf(v, 0.f);
                dst[r * ldD + j * 16 + c16] = f2hs(v);
            }
        }
    }
}

#define HLD 132   // Hf row stride (f32)
#define MLD 136   // Me row stride (fp16)
#define GLD 264   // Gb row stride (fp16)

// (256, 4): 128-VGPR cap. Round-2's (256, 8) forced a 32-VGPR budget and the
// compiler spilled every register array to scratch -> 220 MB of HBM spill
// traffic (FETCH 105 MB / WRITE 123 MB). LDS (18.4 KB) still allows up to
// 8 blocks/CU; VGPR count now decides (6-8 blocks/CU expected).
__global__ __launch_bounds__(256, 4)
void gcn_main(const float* __restrict__ A, const float* __restrict__ X,
              const int* __restrict__ home_mask,
              const float* __restrict__ be1, const float* __restrict__ be2,
              const float* __restrict__ rgcn_b,
              const float* __restrict__ l1b, const float* __restrict__ l2b,
              const float* __restrict__ ln_g, const float* __restrict__ ln_b,
              const float* __restrict__ p1b, const float* __restrict__ p2b,
              const float* __restrict__ r1b, const float* __restrict__ r2w,
              const short* __restrict__ ws, float* __restrict__ out)
{
    const int b   = blockIdx.x;
    const int tid = threadIdx.x;       // 0..255
    const int wv  = tid >> 6;          // wave 0..3
    const int l   = tid & 63;          // lane
    const int q   = l >> 4;
    const int c16 = l & 15;
    const int mrow = (c16 < 10) ? c16 : 9;

    __shared__ __align__(16) float HfS[N_ * HLD];     // residual H, fp32
    __shared__ __align__(16) short Me0S[N_ * MLD];    // mean0 (fp16)
    __shared__ __align__(16) short Me1S[N_ * MLD];    // mean1 (fp16)
    __shared__ __align__(16) short GbS[N_ * GLD];     // staging (256 cols)
    __shared__ __align__(16) short RhoS[2 * 256];     // [hs ; aws] fp16
    __shared__ float AabsS[100], M1S[100];
    __shared__ float invc0S[N_], invc1S[N_];
    __shared__ float hmfS[16], awfS[16];
    __shared__ float dS[4];

    // ---- phase 0: stage A/masks + embed1 (no LDS deps) ----
    if (tid < 100) {
        float a = A[(size_t)b * 100 + tid];
        AabsS[tid] = fabsf(a);
        M1S[tid]  = (a > 0.f) ? 1.f : 0.f;
    }
    if (tid < 16) {
        float hm = 0.f, aw = 0.f;
        if (tid < 10) { hm = (float)home_mask[b * N_ + tid]; aw = 1.f - hm; }
        hmfS[tid] = hm; awfS[tid] = aw;
    }
    {   // embed1: H1 = relu(X@We1 + be1) -> Gb[:,0:128]; wave wv: nt = 2wv..2wv+1
        f32x4 acc[2];
        initC<2>(acc, be1 + wv * 32, c16);
        const float* xg = X + (size_t)b * (N_ * DIN_) + mrow * DIN_ + q * 8;
        f32x4 x0 = *(const f32x4*)xg;
        f32x4 x1 = *(const f32x4*)(xg + 4);
        h16x8 a;
        a[0] = (_Float16)x0[0]; a[1] = (_Float16)x0[1]; a[2] = (_Float16)x0[2]; a[3] = (_Float16)x0[3];
        a[4] = (_Float16)x1[0]; a[5] = (_Float16)x1[1]; a[6] = (_Float16)x1[2]; a[7] = (_Float16)x1[3];
#pragma unroll
        for (int j = 0; j < 2; ++j) {
            h16x8 bv = ld8h(ws + WS_WE1 + ((size_t)(wv * 2 + j) * 64 + l) * 8);
            acc[j] = __builtin_amdgcn_mfma_f32_16x16x32_f16(a, bv, acc[j], 0, 0, 0);
        }
        storeC16<2, true>(acc, GbS + wv * 32, GLD, q, c16);
    }
    __syncthreads();

    // ---- phase 1: invc (from M1S) + embed2 ----
    if (tid < 10) {
        float c1 = 0.f;
#pragma unroll
        for (int i = 0; i < 10; ++i) c1 += M1S[i * 10 + tid];
        invc1S[tid] = 1.f / fmaxf(c1, 1.f);
        invc0S[tid] = 1.f / fmaxf(10.f - c1, 1.f);
    }
    {   // embed2: H = H1@We2 + be2 -> Hf (fp32)
        f32x4 acc[2];
        initC<2>(acc, be2 + wv * 32, c16);
        mm_a16<4, 2>(ws + WS_WE2 + (size_t)wv * 4096, GbS, GLD, mrow, q, l, acc);
        float* hb = HfS + wv * 32;
#pragma unroll
        for (int j = 0; j < 2; ++j)
#pragma unroll
            for (int i = 0; i < 4; ++i) {
                int r = q * 4 + i;
                if (r < 10) hb[r * HLD + j * 16 + c16] = acc[j][i];
            }
    }
    __syncthreads();

    // ---- layers ----
    for (int ll = 0; ll < L_; ++ll) {
        // means: wave wv owns target rows j = wv, wv+4, wv+8 (lane owns cols 2l,2l+1)
        {
            v2f hv[N_];
#pragma unroll
            for (int i = 0; i < N_; ++i) hv[i] = *(const v2f*)(HfS + i * HLD + 2 * l);
            v2f st = hv[0];
#pragma unroll
            for (int i = 1; i < N_; ++i) st += hv[i];
            for (int j = wv; j < 10; j += 4) {
                v2f s1 = splat2(0.f);
#pragma unroll
                for (int i = 0; i < N_; ++i) s1 = fma2(splat2(M1S[i * 10 + j]), hv[i], s1);
                v2f m0 = (st - s1) * splat2(invc0S[j]);
                v2f m1 = s1 * splat2(invc1S[j]);
                short2 w0; w0.x = f2hs(m0.x); w0.y = f2hs(m0.y);
                short2 w1; w1.x = f2hs(m1.x); w1.y = f2hs(m1.y);
                *(short2*)(Me0S + j * MLD + 2 * l) = w0;
                *(short2*)(Me1S + j * MLD + 2 * l) = w1;
            }
        }
        __syncthreads();
        // H2 = mean0@W0 + mean1@W1 + H@root + b -> Gb[:,0:128]
        {
            f32x4 acc[2];
            initC<2>(acc, rgcn_b + ll * D_ + wv * 32, c16);
            mm_a16<4, 2>(ws + WS_RGW + (size_t)(ll * 2 + 0) * 16384 + (size_t)wv * 4096, Me0S, MLD, mrow, q, l, acc);
            mm_a16<4, 2>(ws + WS_RGW + (size_t)(ll * 2 + 1) * 16384 + (size_t)wv * 4096, Me1S, MLD, mrow, q, l, acc);
            mm_a32<4, 2>(ws + WS_RGR + (size_t)ll * 16384 + (size_t)wv * 4096, HfS, HLD, mrow, q, l, acc);
            storeC16<2, false>(acc, GbS + wv * 32, GLD, q, c16);
        }
        __syncthreads();
        // agg + LN + relu: wave wv owns rows i = wv, wv+4, wv+8.
        // reads Gb[:,0:128] (H2), writes Gb[:,128:256] (no in-place hazard).
        {
            v2f lg2 = *(const v2f*)(ln_g + 2 * l);
            v2f lb2 = *(const v2f*)(ln_b + 2 * l);
            v2f hv2[N_];
#pragma unroll
            for (int jj = 0; jj < N_; ++jj) {
                short2 hh = *(const short2*)(GbS + jj * GLD + 2 * l);
                hv2[jj].x = hs2f(hh.x); hv2[jj].y = hs2f(hh.y);
            }
            for (int i = wv; i < 10; i += 4) {
                v2f ag = splat2(0.f);
#pragma unroll
                for (int jj = 0; jj < N_; ++jj)
                    ag = fma2(splat2(AabsS[i * 10 + jj]), hv2[jj], ag);
                float s  = ag.x + ag.y;
                float ss = fmaf(ag.x, ag.x, ag.y * ag.y);
#pragma unroll
                for (int off = 32; off > 0; off >>= 1) {
                    s  += __shfl_xor(s,  off);
                    ss += __shfl_xor(ss, off);
                }
                float mu   = s * (1.f / 128.f);
                float var  = ss * (1.f / 128.f) - mu * mu;
                float rstd = rsqrtf(var + EPS_);
                v2f v = fma2((ag - splat2(mu)) * splat2(rstd), lg2, lb2);
                short2 wvv; wvv.x = f2hs(fmaxf(v.x, 0.f)); wvv.y = f2hs(fmaxf(v.y, 0.f));
                *(short2*)(GbS + i * GLD + 128 + 2 * l) = wvv;
            }
        }
        __syncthreads();
        // MLP1: relu(LNout @ l1w + l1b): reads Gb[:,128:256], writes Gb[:,0:128]
        {
            f32x4 acc[2];
            initC<2>(acc, l1b + ll * D_ + wv * 32, c16);
            mm_a16<4, 2>(ws + WS_L1 + (size_t)ll * 16384 + (size_t)wv * 4096, GbS + 128, GLD, mrow, q, l, acc);
            storeC16<2, true>(acc, GbS + wv * 32, GLD, q, c16);
        }
        __syncthreads();
        // MLP2: hidden @ l2w + l2b: reads Gb[:,0:128], Hf += result
        {
            f32x4 acc[2];
            initC<2>(acc, l2b + ll * D_ + wv * 32, c16);
            mm_a16<4, 2>(ws + WS_L2 + (size_t)ll * 16384 + (size_t)wv * 4096, GbS, GLD, mrow, q, l, acc);
            float* hb = HfS + wv * 32;
#pragma unroll
            for (int j = 0; j < 2; ++j)
#pragma unroll
                for (int i = 0; i < 4; ++i) {
                    int r = q * 4 + i;
                    if (r < 10) hb[r * HLD + j * 16 + c16] += acc[j][i];
                }
        }
        __syncthreads();
    }

    // ---- phi1: relu(H @ p1w + p1b) -> Gb[:,0:256]; wave wv: nt = 4wv..4wv+3 ----
    {
        f32x4 acc[4];
        initC<4>(acc, p1b + wv * 64, c16);
        mm_a32<4, 4>(ws + WS_P1 + (size_t)wv * 8192, HfS, HLD, mrow, q, l, acc);
        storeC16<4, true>(acc, GbS + wv * 64, GLD, q, c16);
    }
    __syncthreads();
    // ---- phi2 + masked column sums -> RhoS [hs;aws]; wave wv: t = 4wv..4wv+3 ----
    {
        f32x4 acc[4];
        initC<4>(acc, p2b + wv * 64, c16);
        mm_a16<8, 4>(ws + WS_P2 + (size_t)wv * 16384, GbS, GLD, mrow, q, l, acc);
        float hm0 = hmfS[q * 4 + 0], hm1 = hmfS[q * 4 + 1], hm2 = hmfS[q * 4 + 2], hm3 = hmfS[q * 4 + 3];
        float aw0 = awfS[q * 4 + 0], aw1 = awfS[q * 4 + 1], aw2 = awfS[q * 4 + 2], aw3 = awfS[q * 4 + 3];
#pragma unroll
        for (int t = 0; t < 4; ++t) {
            float v0 = fmaxf(acc[t][0], 0.f), v1 = fmaxf(acc[t][1], 0.f);
            float v2 = fmaxf(acc[t][2], 0.f), v3 = fmaxf(acc[t][3], 0.f);
            float hp = hm0 * v0 + hm1 * v1 + hm2 * v2 + hm3 * v3;
            float ap = aw0 * v0 + aw1 * v1 + aw2 * v2 + aw3 * v3;
            hp += __shfl_xor(hp, 16); hp += __shfl_xor(hp, 32);
            ap += __shfl_xor(ap, 16); ap += __shfl_xor(ap, 32);
            if (l < 16) {
                RhoS[(wv * 4 + t) * 16 + l]       = f2hs(hp);
                RhoS[256 + (wv * 4 + t) * 16 + l] = f2hs(ap);
            }
        }
    }
    __syncthreads();
    // ---- rho: relu([hs;aws] @ r1w + r1b) @ r2w; wave wv: t = 2wv..2wv+1 ----
    {
        f32x4 acc[2];
        initC<2>(acc, r1b + wv * 32, c16);
        const int rr = (c16 < 2) ? c16 : 0;
        mm_a16<8, 2>(ws + WS_R1 + (size_t)wv * 8192, RhoS, 256, rr, q, l, acc);
        float d = 0.f;
        if (q == 0) {
#pragma unroll
            for (int t = 0; t < 2; ++t) {
                float vh = fmaxf(acc[t][0], 0.f);
                float va = fmaxf(acc[t][1], 0.f);
                d = fmaf(vh - va, r2w[(wv * 2 + t) * 16 + c16], d);
            }
        }
#pragma unroll
        for (int off = 32; off > 0; off >>= 1) d += __shfl_xor(d, off);
        if (l == 0) dS[wv] = d;
    }
    __syncthreads();
    if (tid == 0) out[b] = 0.5f + 0.5f * tanhf(dS[0] + dS[1] + dS[2] + dS[3]);
}

extern "C" void kernel_launch(void* const* d_in, const int* in_sizes, int n_in,
                              void* d_out, int out_size, void* d_ws, size_t ws_size,
                              hipStream_t stream) {
    const float* A         = (const float*)d_in[0];
    const float* X         = (const float*)d_in[1];
    const int*   home_mask = (const int*)  d_in[2];
    const float* We1       = (const float*)d_in[3];
    const float* be1       = (const float*)d_in[4];
    const float* We2       = (const float*)d_in[5];
    const float* be2       = (const float*)d_in[6];
    const float* rgcn_w    = (const float*)d_in[7];
    const float* rgcn_root = (const float*)d_in[8];
    const float* rgcn_b    = (const float*)d_in[9];
    const float* l1w       = (const float*)d_in[10];
    const float* l1b       = (const float*)d_in[11];
    const float* l2w       = (const float*)d_in[12];
    const float* l2b       = (const float*)d_in[13];
    const float* ln_g      = (const float*)d_in[14];
    const float* ln_b      = (const float*)d_in[15];
    const float* p1w       = (const float*)d_in[16];
    const float* p1b       = (const float*)d_in[17];
    const float* p2w       = (const float*)d_in[18];
    const float* p2b       = (const float*)d_in[19];
    const float* r1w       = (const float*)d_in[20];
    const float* r1b       = (const float*)d_in[21];
    const float* r2w       = (const float*)d_in[22];

    short* ws = (short*)d_ws;

    prep_weights<<<776, 64, 0, stream>>>(We1, We2, rgcn_w, rgcn_root,
                                         l1w, l2w, p1w, p2w, r1w, ws);
    gcn_main<<<B_, 256, 0, stream>>>(A, X, home_mask, be1, be2, rgcn_b,
                                     l1b, l2b, ln_g, ln_b, p1b, p2b,
                                     r1b, r2w, ws, (float*)d_out);
}